// Round 19
// baseline (225.664 us; speedup 1.0000x reference)
//
#include <hip/hip_runtime.h>

#define BB   1024
#define TT   512
#define NIN  28
#define NS   4
#define MM   7
#define WW   457          // TT - 28 - 28 + 1
#define SLEN 519
#define EMB  9

#define OUT1_SZ (WW * BB * 144)
#define OUT2_SZ (WW * BB * 28)
#define OUT3_SZ (BB * TT)
#define OUT4_SZ (BB * SLEN)

#define CH   32
#define NCH  (TT / CH)
#define NF2  (WW * BB * 7)

typedef float f4 __attribute__((ext_vector_type(4)));

__device__ __forceinline__ f4 ld4u(const float* p) {
    f4 v;
    __builtin_memcpy(&v, p, sizeof(f4));
    return v;
}

// ---------------------------------------------------------------------------
// Kernel 1: ES scan (R4 version, proven ~10 us, runs alone).
// ---------------------------------------------------------------------------
__global__ __launch_bounds__(64) void es_scan(const float* __restrict__ Y,
        const int* __restrict__ idxs, const float* __restrict__ EW,
        float* __restrict__ levels, float* __restrict__ seas) {
    __shared__ float yl[64][CH + 1];
    __shared__ float se[64][CH + 1];
    const int tid = threadIdx.x;
    const int b0  = blockIdx.x << 6;
    const int b   = b0 + tid;

    const float* e = EW + idxs[b] * EMB;
    const float lev_sms  = 1.0f / (1.0f + __expf(-e[0]));
    const float seas_sms = 1.0f / (1.0f + __expf(-e[1]));
    const float a_l = 1.0f - lev_sms;
    const float a_s = 1.0f - seas_sms;

    float buf[MM];
    const float is0 = __expf(e[2]);
    {
        float* srow = seas + b * SLEN;
        srow[0] = is0;
#pragma unroll
        for (int k = 1; k < MM; ++k) {
            float v = __expf(e[2 + k]);
            srow[k] = v;
            buf[k - 1] = v;
        }
        buf[MM - 1] = is0;
    }

    f4 pf[8];
#pragma unroll
    for (int k = 0; k < 8; ++k) {
        int flat = (k << 6) + tid;
        int r = flat >> 3, q = flat & 7;
        pf[k] = *reinterpret_cast<const f4*>(Y + (b0 + r) * TT + (q << 2));
    }

    float lev = 0.0f;

#define ES_STEP(TTI)                                                        \
    {                                                                       \
        float y  = yreg[TTI];                                               \
        float st = buf[0];                                                  \
        lev = lev_sms * __fdividef(y, st) + a_l * lev;                      \
        float ns = seas_sms * __fdividef(y, lev) + a_s * st;                \
        buf[0] = buf[1]; buf[1] = buf[2]; buf[2] = buf[3];                  \
        buf[3] = buf[4]; buf[4] = buf[5]; buf[5] = buf[6];                  \
        buf[6] = ns;                                                        \
        yl[tid][TTI] = lev;                                                 \
        se[tid][TTI] = ns;                                                  \
    }

    for (int c = 0; c < NCH; ++c) {
        __syncthreads();
#pragma unroll
        for (int k = 0; k < 8; ++k) {
            int flat = (k << 6) + tid;
            int r = flat >> 3, q = flat & 7;
            float* dst = &yl[r][q << 2];
            dst[0] = pf[k].x; dst[1] = pf[k].y; dst[2] = pf[k].z; dst[3] = pf[k].w;
        }
        __syncthreads();
        if (c < NCH - 1) {
#pragma unroll
            for (int k = 0; k < 8; ++k) {
                int flat = (k << 6) + tid;
                int r = flat >> 3, q = flat & 7;
                pf[k] = *reinterpret_cast<const f4*>(
                    Y + (b0 + r) * TT + (c + 1) * CH + (q << 2));
            }
        }

        float yreg[CH];
#pragma unroll
        for (int tt = 0; tt < CH; ++tt) yreg[tt] = yl[tid][tt];

        if (c == 0) {
            lev = __fdividef(yreg[0], is0);
            yl[tid][0] = lev;
            se[tid][0] = is0;
#pragma unroll
            for (int tt = 1; tt < CH; ++tt) ES_STEP(tt)
        } else {
#pragma unroll
            for (int tt = 0; tt < CH; ++tt) ES_STEP(tt)
        }
        __syncthreads();

#pragma unroll
        for (int k = 0; k < CH; ++k) {
            int flat = (k << 6) + tid;
            int r    = flat >> 5;
            int col  = flat & 31;
            levels[(b0 + r) * TT   + c * CH + col]      = yl[r][col];
            seas  [(b0 + r) * SLEN + MM + c * CH + col] = se[r][col];
        }
    }
#undef ES_STEP
}

// ---------------------------------------------------------------------------
// Kernel 2 PROBE: R16's pipelined k_out1, with each tile's store phase
// repeated 3x (idempotent, output correct). dur = A + 3S; R16's known
// A + S = ~94 => solves A and S. Counters become top-5 visible.
// ---------------------------------------------------------------------------
#define LYSo 0
#define LYSs 273
#define XSo  546
#define XSs  293
#define LLo  1718
#define LLs  237
#define SSo  2192
#define ZRo  2200
#define ULEN 2201
#define OST  (7 * 1024 * 36)

__device__ __forceinline__ void tload(int i, int g0, int b0,
        const float* __restrict__ Y, const float* __restrict__ seas,
        const float* __restrict__ X, const float* __restrict__ levels,
        f4& a, f4& b) {
    if (i < 128) {
        int bl = i >> 6, k = i & 63, t = g0 + (k << 2);
        a = ld4u(Y    + (b0 + bl) * TT   + t);
        b = ld4u(seas + (b0 + bl) * SLEN + t);
    } else if (i < 412) {
        int j = i - 128, blc = j / 71, k = j - blc * 71;
        int t = g0 + (k << 2); if (t > 508) t = 508;
        a = ld4u(X + (size_t)((b0 + (blc >> 1)) * 2 + (blc & 1)) * TT + t);
    } else if (i < 528) {
        int j = i - 412, bl = j / 58, k = j - bl * 58;
        a = ld4u(levels + (b0 + bl) * TT + g0 + 24 + (k << 2));
    }
}

__device__ __forceinline__ void twrite(int i, int g0, float* U, f4 a, f4 b) {
    if (i < 128) {
        int bl = i >> 6, k = i & 63, base = LYSo + bl * LYSs + (k << 2);
        U[base + 0] = __logf(a.x) - __logf(b.x);
        U[base + 1] = __logf(a.y) - __logf(b.y);
        U[base + 2] = __logf(a.z) - __logf(b.z);
        U[base + 3] = __logf(a.w) - __logf(b.w);
    } else if (i < 412) {
        int j = i - 128, blc = j / 71, k = j - blc * 71;
        int wb = (k << 2); if (g0 + wb > 508) wb = 508 - g0;
        int base = XSo + blc * XSs + wb;
        U[base + 0] = a.x; U[base + 1] = a.y;
        U[base + 2] = a.z; U[base + 3] = a.w;
    } else if (i < 528) {
        int j = i - 412, bl = j / 58, k = j - bl * 58;
        int base = LLo + bl * LLs + (k << 2);
        U[base + 0] = __logf(a.x); U[base + 1] = __logf(a.y);
        U[base + 2] = __logf(a.z); U[base + 3] = __logf(a.w);
    }
}

__device__ __forceinline__ void tstore(int tid, int g0, int NW, int b0,
        const float* U, f4* __restrict__ out1) {
    if (tid >= 504) return;
    int go  = tid / 72;
    int r   = tid - go * 72;
    int bl  = (r >= 36) ? 1 : 0;
    int col = r - 36 * bl;
    int pa, la, dp, dl;
    if (col < 7) {
        pa = LYSo + bl * LYSs + go + (col << 2);
        la = LLo  + bl * LLs  + go + 3;
        dp = 7; dl = 7;
    } else if (col < 35) {
        int ch = (col >= 21) ? 1 : 0;
        int jj = col - 7 - 14 * ch;
        pa = XSo + ((bl << 1) | ch) * XSs + go + (jj << 2);
        la = ZRo; dp = 7; dl = 0;
    } else {
        pa = SSo + (bl << 2);
        la = ZRo; dp = 0; dl = 0;
    }
    int off = (((g0 + go) << 10) + b0 + bl) * 36 + col;
#define ST1 { float l = U[la]; f4 v;                                        \
    v.x = U[pa] - l; v.y = U[pa + 1] - l;                                   \
    v.z = U[pa + 2] - l; v.w = U[pa + 3] - l;                               \
    __builtin_nontemporal_store(v, out1 + off);                             \
    pa += dp; la += dl; off += OST; }
#pragma unroll 4
    for (int t = 0; t < 32; ++t) ST1
    if (go + 224 < NW) ST1
#undef ST1
}

__global__ __launch_bounds__(512) void k_out1_probe(const float* __restrict__ Y,
        const float* __restrict__ X, const float* __restrict__ S,
        const float* __restrict__ levels, const float* __restrict__ seas,
        f4* __restrict__ out1) {
    __shared__ float U[ULEN];
    const int tid = threadIdx.x;
    const int b0  = (int)blockIdx.x << 1;

    f4 a, b, e, eb, a2, b2, e2, eb2, sv;

    tload(tid, 0, b0, Y, seas, X, levels, a, b);
    if (tid < 16) tload(512 + tid, 0, b0, Y, seas, X, levels, e, eb);
    if (tid < 2)  sv = *reinterpret_cast<const f4*>(S + ((b0 + tid) << 2));

    twrite(tid, 0, U, a, b);
    if (tid < 16) twrite(512 + tid, 0, U, e, eb);
    if (tid < 2) {
        int base = SSo + (tid << 2);
        U[base] = sv.x; U[base + 1] = sv.y; U[base + 2] = sv.z; U[base + 3] = sv.w;
    }
    if (tid == 2) U[ZRo] = 0.0f;
    __syncthreads();

    tload(tid, 229, b0, Y, seas, X, levels, a2, b2);
    if (tid < 16) tload(512 + tid, 229, b0, Y, seas, X, levels, e2, eb2);

    for (int rep = 0; rep < 3; ++rep)            // PROBE: 3x store phase
        tstore(tid, 0, 229, b0, U, out1);
    __syncthreads();

    twrite(tid, 229, U, a2, b2);
    if (tid < 16) twrite(512 + tid, 229, U, e2, eb2);
    __syncthreads();

    for (int rep = 0; rep < 3; ++rep)            // PROBE: 3x store phase
        tstore(tid, 229, 228, b0, U, out1);
}

// ---------------------------------------------------------------------------
// Kernel 3: out2 + out5 (R14/R16 flat dense, nt stores, ~17 us).
// ---------------------------------------------------------------------------
__global__ __launch_bounds__(256) void k_out25(const float* __restrict__ Y,
        const float* __restrict__ mask, f4* __restrict__ out2,
        f4* __restrict__ out5) {
    int i = blockIdx.x * blockDim.x + threadIdx.x;
    const int stride = gridDim.x * blockDim.x;
    for (; i < NF2; i += stride) {
        int wb = i / 7;
        int j  = i - wb * 7;
        int b  = wb & (BB - 1);
        int w  = wb >> 10;
        int base = w + NIN + (j << 2);
        f4 vy = ld4u(Y    + b * TT + base);
        f4 vm = ld4u(mask + b * TT + base);
        __builtin_nontemporal_store(vy, &out2[i]);
        __builtin_nontemporal_store(vm, &out5[i]);
    }
}

extern "C" void kernel_launch(void* const* d_in, const int* in_sizes, int n_in,
                              void* d_out, int out_size, void* d_ws, size_t ws_size,
                              hipStream_t stream) {
    const float* S    = (const float*)d_in[0];
    const float* Y    = (const float*)d_in[1];
    const float* X    = (const float*)d_in[2];
    const int*   idxs = (const int*)d_in[3];
    const float* mask = (const float*)d_in[4];
    const float* EW   = (const float*)d_in[5];

    float* out  = (float*)d_out;
    float* out1 = out;
    float* out2 = out1 + OUT1_SZ;
    float* out3 = out2 + OUT2_SZ;        // levels
    float* out4 = out3 + OUT3_SZ;        // seasonalities
    float* out5 = out4 + OUT4_SZ;        // mask_w

    es_scan<<<16, 64, 0, stream>>>(Y, idxs, EW, out3, out4);
    k_out1_probe<<<512, 512, 0, stream>>>(Y, X, S, out3, out4, (f4*)out1);
    k_out25<<<2048, 256, 0, stream>>>(Y, mask, (f4*)out2, (f4*)out5);
}

// Round 20
// 127.285 us; speedup vs baseline: 1.7729x; 1.7729x over previous
//
#include <hip/hip_runtime.h>

#define BB   1024
#define TT   512
#define NIN  28
#define NS   4
#define MM   7
#define WW   457          // TT - 28 - 28 + 1
#define SLEN 519
#define EMB  9

#define OUT1_SZ (WW * BB * 144)
#define OUT2_SZ (WW * BB * 28)
#define OUT3_SZ (BB * TT)
#define OUT4_SZ (BB * SLEN)

#define CH   32
#define NCH  (TT / CH)
#define NF2  (WW * BB * 7)

typedef float f4 __attribute__((ext_vector_type(4)));

__device__ __forceinline__ f4 ld4u(const float* p) {
    f4 v;
    __builtin_memcpy(&v, p, sizeof(f4));
    return v;
}

// ---------------------------------------------------------------------------
// Kernel 1: ES scan (R4 version, proven ~10 us, runs alone — R18 lesson:
// never co-schedule the latency-critical scan with bandwidth hogs).
// ---------------------------------------------------------------------------
__global__ __launch_bounds__(64) void es_scan(const float* __restrict__ Y,
        const int* __restrict__ idxs, const float* __restrict__ EW,
        float* __restrict__ levels, float* __restrict__ seas) {
    __shared__ float yl[64][CH + 1];
    __shared__ float se[64][CH + 1];
    const int tid = threadIdx.x;
    const int b0  = blockIdx.x << 6;
    const int b   = b0 + tid;

    const float* e = EW + idxs[b] * EMB;
    const float lev_sms  = 1.0f / (1.0f + __expf(-e[0]));
    const float seas_sms = 1.0f / (1.0f + __expf(-e[1]));
    const float a_l = 1.0f - lev_sms;
    const float a_s = 1.0f - seas_sms;

    float buf[MM];
    const float is0 = __expf(e[2]);
    {
        float* srow = seas + b * SLEN;
        srow[0] = is0;
#pragma unroll
        for (int k = 1; k < MM; ++k) {
            float v = __expf(e[2 + k]);
            srow[k] = v;
            buf[k - 1] = v;
        }
        buf[MM - 1] = is0;
    }

    f4 pf[8];
#pragma unroll
    for (int k = 0; k < 8; ++k) {
        int flat = (k << 6) + tid;
        int r = flat >> 3, q = flat & 7;
        pf[k] = *reinterpret_cast<const f4*>(Y + (b0 + r) * TT + (q << 2));
    }

    float lev = 0.0f;

#define ES_STEP(TTI)                                                        \
    {                                                                       \
        float y  = yreg[TTI];                                               \
        float st = buf[0];                                                  \
        lev = lev_sms * __fdividef(y, st) + a_l * lev;                      \
        float ns = seas_sms * __fdividef(y, lev) + a_s * st;                \
        buf[0] = buf[1]; buf[1] = buf[2]; buf[2] = buf[3];                  \
        buf[3] = buf[4]; buf[4] = buf[5]; buf[5] = buf[6];                  \
        buf[6] = ns;                                                        \
        yl[tid][TTI] = lev;                                                 \
        se[tid][TTI] = ns;                                                  \
    }

    for (int c = 0; c < NCH; ++c) {
        __syncthreads();
#pragma unroll
        for (int k = 0; k < 8; ++k) {
            int flat = (k << 6) + tid;
            int r = flat >> 3, q = flat & 7;
            float* dst = &yl[r][q << 2];
            dst[0] = pf[k].x; dst[1] = pf[k].y; dst[2] = pf[k].z; dst[3] = pf[k].w;
        }
        __syncthreads();
        if (c < NCH - 1) {
#pragma unroll
            for (int k = 0; k < 8; ++k) {
                int flat = (k << 6) + tid;
                int r = flat >> 3, q = flat & 7;
                pf[k] = *reinterpret_cast<const f4*>(
                    Y + (b0 + r) * TT + (c + 1) * CH + (q << 2));
            }
        }

        float yreg[CH];
#pragma unroll
        for (int tt = 0; tt < CH; ++tt) yreg[tt] = yl[tid][tt];

        if (c == 0) {
            lev = __fdividef(yreg[0], is0);
            yl[tid][0] = lev;
            se[tid][0] = is0;
#pragma unroll
            for (int tt = 1; tt < CH; ++tt) ES_STEP(tt)
        } else {
#pragma unroll
            for (int tt = 0; tt < CH; ++tt) ES_STEP(tt)
        }
        __syncthreads();

#pragma unroll
        for (int k = 0; k < CH; ++k) {
            int flat = (k << 6) + tid;
            int r    = flat >> 5;
            int col  = flat & 31;
            levels[(b0 + r) * TT   + c * CH + col]      = yl[r][col];
            seas  [(b0 + r) * SLEN + MM + c * CH + col] = se[r][col];
        }
    }
#undef ES_STEP
}

// ---------------------------------------------------------------------------
// Kernel 2 (fused): out1 (R16 pipelined body) + out2/out5 (flat dense body),
// interleaved blockIdx%3 -> each CU hosts both kinds. out25's pure store
// stream keeps HBM saturated while out1 blocks stage/logf/barrier (A~44us
// hidden under S). 1536 blocks x 512 thr.
// ---------------------------------------------------------------------------
#define LYSo 0
#define LYSs 273
#define XSo  546
#define XSs  293
#define LLo  1718
#define LLs  237
#define SSo  2192
#define ZRo  2200
#define ULEN 2201
#define OST  (7 * 1024 * 36)

__device__ __forceinline__ void tload(int i, int g0, int b0,
        const float* __restrict__ Y, const float* __restrict__ seas,
        const float* __restrict__ X, const float* __restrict__ levels,
        f4& a, f4& b) {
    if (i < 128) {
        int bl = i >> 6, k = i & 63, t = g0 + (k << 2);
        a = ld4u(Y    + (b0 + bl) * TT   + t);
        b = ld4u(seas + (b0 + bl) * SLEN + t);
    } else if (i < 412) {
        int j = i - 128, blc = j / 71, k = j - blc * 71;
        int t = g0 + (k << 2); if (t > 508) t = 508;
        a = ld4u(X + (size_t)((b0 + (blc >> 1)) * 2 + (blc & 1)) * TT + t);
    } else if (i < 528) {
        int j = i - 412, bl = j / 58, k = j - bl * 58;
        a = ld4u(levels + (b0 + bl) * TT + g0 + 24 + (k << 2));
    }
}

__device__ __forceinline__ void twrite(int i, int g0, float* U, f4 a, f4 b) {
    if (i < 128) {
        int bl = i >> 6, k = i & 63, base = LYSo + bl * LYSs + (k << 2);
        U[base + 0] = __logf(a.x) - __logf(b.x);
        U[base + 1] = __logf(a.y) - __logf(b.y);
        U[base + 2] = __logf(a.z) - __logf(b.z);
        U[base + 3] = __logf(a.w) - __logf(b.w);
    } else if (i < 412) {
        int j = i - 128, blc = j / 71, k = j - blc * 71;
        int wb = (k << 2); if (g0 + wb > 508) wb = 508 - g0;
        int base = XSo + blc * XSs + wb;
        U[base + 0] = a.x; U[base + 1] = a.y;
        U[base + 2] = a.z; U[base + 3] = a.w;
    } else if (i < 528) {
        int j = i - 412, bl = j / 58, k = j - bl * 58;
        int base = LLo + bl * LLs + (k << 2);
        U[base + 0] = __logf(a.x); U[base + 1] = __logf(a.y);
        U[base + 2] = __logf(a.z); U[base + 3] = __logf(a.w);
    }
}

__device__ __forceinline__ void tstore(int tid, int g0, int NW, int b0,
        const float* U, f4* __restrict__ out1) {
    if (tid >= 504) return;
    int go  = tid / 72;
    int r   = tid - go * 72;
    int bl  = (r >= 36) ? 1 : 0;
    int col = r - 36 * bl;
    int pa, la, dp, dl;
    if (col < 7) {
        pa = LYSo + bl * LYSs + go + (col << 2);
        la = LLo  + bl * LLs  + go + 3;
        dp = 7; dl = 7;
    } else if (col < 35) {
        int ch = (col >= 21) ? 1 : 0;
        int jj = col - 7 - 14 * ch;
        pa = XSo + ((bl << 1) | ch) * XSs + go + (jj << 2);
        la = ZRo; dp = 7; dl = 0;
    } else {
        pa = SSo + (bl << 2);
        la = ZRo; dp = 0; dl = 0;
    }
    int off = (((g0 + go) << 10) + b0 + bl) * 36 + col;
#define ST1 { float l = U[la]; f4 v;                                        \
    v.x = U[pa] - l; v.y = U[pa + 1] - l;                                   \
    v.z = U[pa + 2] - l; v.w = U[pa + 3] - l;                               \
    __builtin_nontemporal_store(v, out1 + off);                             \
    pa += dp; la += dl; off += OST; }
#pragma unroll 4
    for (int t = 0; t < 32; ++t) ST1
    if (go + 224 < NW) ST1
#undef ST1
}

__global__ __launch_bounds__(512) void fused_stream(const float* __restrict__ Y,
        const float* __restrict__ X, const float* __restrict__ S,
        const float* __restrict__ mask, const float* __restrict__ levels,
        const float* __restrict__ seas, f4* __restrict__ out1,
        f4* __restrict__ out2, f4* __restrict__ out5) {
    __shared__ float U[ULEN];
    const int tid = threadIdx.x;
    const int r3  = blockIdx.x % 3;
    const int q3  = blockIdx.x / 3;

    if (r3 == 0) {
        // ==================== out1 (R16 body) ====================
        const int b0 = q3 << 1;
        f4 a, b, e, eb, a2, b2, e2, eb2, sv;

        tload(tid, 0, b0, Y, seas, X, levels, a, b);
        if (tid < 16) tload(512 + tid, 0, b0, Y, seas, X, levels, e, eb);
        if (tid < 2)  sv = *reinterpret_cast<const f4*>(S + ((b0 + tid) << 2));

        twrite(tid, 0, U, a, b);
        if (tid < 16) twrite(512 + tid, 0, U, e, eb);
        if (tid < 2) {
            int base = SSo + (tid << 2);
            U[base] = sv.x; U[base + 1] = sv.y;
            U[base + 2] = sv.z; U[base + 3] = sv.w;
        }
        if (tid == 2) U[ZRo] = 0.0f;
        __syncthreads();

        tload(tid, 229, b0, Y, seas, X, levels, a2, b2);
        if (tid < 16) tload(512 + tid, 229, b0, Y, seas, X, levels, e2, eb2);

        tstore(tid, 0, 229, b0, U, out1);
        __syncthreads();

        twrite(tid, 229, U, a2, b2);
        if (tid < 16) twrite(512 + tid, 229, U, e2, eb2);
        __syncthreads();

        tstore(tid, 229, 228, b0, U, out1);
    } else {
        // ==================== out2 + out5 ====================
        const int id = (q3 << 1) + (r3 - 1);      // 0..1023
        for (int i = (id << 9) + tid; i < NF2; i += 1024 * 512) {
            int wb = i / 7;
            int j  = i - wb * 7;
            int b  = wb & (BB - 1);
            int w  = wb >> 10;
            int base = w + NIN + (j << 2);
            f4 vy = ld4u(Y    + b * TT + base);
            f4 vm = ld4u(mask + b * TT + base);
            __builtin_nontemporal_store(vy, &out2[i]);
            __builtin_nontemporal_store(vm, &out5[i]);
        }
    }
}

extern "C" void kernel_launch(void* const* d_in, const int* in_sizes, int n_in,
                              void* d_out, int out_size, void* d_ws, size_t ws_size,
                              hipStream_t stream) {
    const float* S    = (const float*)d_in[0];
    const float* Y    = (const float*)d_in[1];
    const float* X    = (const float*)d_in[2];
    const int*   idxs = (const int*)d_in[3];
    const float* mask = (const float*)d_in[4];
    const float* EW   = (const float*)d_in[5];

    float* out  = (float*)d_out;
    float* out1 = out;
    float* out2 = out1 + OUT1_SZ;
    float* out3 = out2 + OUT2_SZ;        // levels
    float* out4 = out3 + OUT3_SZ;        // seasonalities
    float* out5 = out4 + OUT4_SZ;        // mask_w

    es_scan<<<16, 64, 0, stream>>>(Y, idxs, EW, out3, out4);
    fused_stream<<<1536, 512, 0, stream>>>(Y, X, S, mask, out3, out4,
                                           (f4*)out1, (f4*)out2, (f4*)out5);
}

// Round 21
// 117.364 us; speedup vs baseline: 1.9228x; 1.0845x over previous
//
#include <hip/hip_runtime.h>

#define BB   1024
#define TT   512
#define NIN  28
#define NS   4
#define MM   7
#define WW   457          // TT - 28 - 28 + 1
#define SLEN 519
#define EMB  9

#define OUT1_SZ (WW * BB * 144)
#define OUT2_SZ (WW * BB * 28)
#define OUT3_SZ (BB * TT)
#define OUT4_SZ (BB * SLEN)

#define CH   32
#define NCH  (TT / CH)
#define NF1  (WW * BB * 36)
#define NF2  (WW * BB * 7)

typedef float f4 __attribute__((ext_vector_type(4)));

__device__ __forceinline__ f4 ld4u(const float* p) {
    f4 v;
    __builtin_memcpy(&v, p, sizeof(f4));
    return v;
}

// ---------------------------------------------------------------------------
// Kernel 1: ES scan (R4 version, proven ~10 us, runs alone).
// ---------------------------------------------------------------------------
__global__ __launch_bounds__(64) void es_scan(const float* __restrict__ Y,
        const int* __restrict__ idxs, const float* __restrict__ EW,
        float* __restrict__ levels, float* __restrict__ seas) {
    __shared__ float yl[64][CH + 1];
    __shared__ float se[64][CH + 1];
    const int tid = threadIdx.x;
    const int b0  = blockIdx.x << 6;
    const int b   = b0 + tid;

    const float* e = EW + idxs[b] * EMB;
    const float lev_sms  = 1.0f / (1.0f + __expf(-e[0]));
    const float seas_sms = 1.0f / (1.0f + __expf(-e[1]));
    const float a_l = 1.0f - lev_sms;
    const float a_s = 1.0f - seas_sms;

    float buf[MM];
    const float is0 = __expf(e[2]);
    {
        float* srow = seas + b * SLEN;
        srow[0] = is0;
#pragma unroll
        for (int k = 1; k < MM; ++k) {
            float v = __expf(e[2 + k]);
            srow[k] = v;
            buf[k - 1] = v;
        }
        buf[MM - 1] = is0;
    }

    f4 pf[8];
#pragma unroll
    for (int k = 0; k < 8; ++k) {
        int flat = (k << 6) + tid;
        int r = flat >> 3, q = flat & 7;
        pf[k] = *reinterpret_cast<const f4*>(Y + (b0 + r) * TT + (q << 2));
    }

    float lev = 0.0f;

#define ES_STEP(TTI)                                                        \
    {                                                                       \
        float y  = yreg[TTI];                                               \
        float st = buf[0];                                                  \
        lev = lev_sms * __fdividef(y, st) + a_l * lev;                      \
        float ns = seas_sms * __fdividef(y, lev) + a_s * st;                \
        buf[0] = buf[1]; buf[1] = buf[2]; buf[2] = buf[3];                  \
        buf[3] = buf[4]; buf[4] = buf[5]; buf[5] = buf[6];                  \
        buf[6] = ns;                                                        \
        yl[tid][TTI] = lev;                                                 \
        se[tid][TTI] = ns;                                                  \
    }

    for (int c = 0; c < NCH; ++c) {
        __syncthreads();
#pragma unroll
        for (int k = 0; k < 8; ++k) {
            int flat = (k << 6) + tid;
            int r = flat >> 3, q = flat & 7;
            float* dst = &yl[r][q << 2];
            dst[0] = pf[k].x; dst[1] = pf[k].y; dst[2] = pf[k].z; dst[3] = pf[k].w;
        }
        __syncthreads();
        if (c < NCH - 1) {
#pragma unroll
            for (int k = 0; k < 8; ++k) {
                int flat = (k << 6) + tid;
                int r = flat >> 3, q = flat & 7;
                pf[k] = *reinterpret_cast<const f4*>(
                    Y + (b0 + r) * TT + (c + 1) * CH + (q << 2));
            }
        }

        float yreg[CH];
#pragma unroll
        for (int tt = 0; tt < CH; ++tt) yreg[tt] = yl[tid][tt];

        if (c == 0) {
            lev = __fdividef(yreg[0], is0);
            yl[tid][0] = lev;
            se[tid][0] = is0;
#pragma unroll
            for (int tt = 1; tt < CH; ++tt) ES_STEP(tt)
        } else {
#pragma unroll
            for (int tt = 0; tt < CH; ++tt) ES_STEP(tt)
        }
        __syncthreads();

#pragma unroll
        for (int k = 0; k < CH; ++k) {
            int flat = (k << 6) + tid;
            int r    = flat >> 5;
            int col  = flat & 31;
            levels[(b0 + r) * TT   + c * CH + col]      = yl[r][col];
            seas  [(b0 + r) * SLEN + MM + c * CH + col] = se[r][col];
        }
    }
#undef ES_STEP
}

// ---------------------------------------------------------------------------
// Kernel 2: precompute LL = log(levels), LYS = log(Y) - log(seas) into d_ws
// (4 MB, L2-resident). 512 blocks x 256 thr, one f4 each. ~3 us.
// ---------------------------------------------------------------------------
__global__ __launch_bounds__(256) void k_pre(const float* __restrict__ levels,
        const float* __restrict__ seas, const float* __restrict__ Y,
        float* __restrict__ LL, float* __restrict__ LYS) {
    int u  = blockIdx.x * 256 + threadIdx.x;    // f4 index < 131072
    int b  = u >> 7;
    int t4 = (u & 127) << 2;
    f4 lv = *reinterpret_cast<const f4*>(levels + b * TT + t4);
    f4 yv = *reinterpret_cast<const f4*>(Y      + b * TT + t4);
    f4 sv = ld4u(seas + b * SLEN + t4);
    f4 a, c;
    a.x = __logf(lv.x); a.y = __logf(lv.y); a.z = __logf(lv.z); a.w = __logf(lv.w);
    c.x = __logf(yv.x) - __logf(sv.x);
    c.y = __logf(yv.y) - __logf(sv.y);
    c.z = __logf(yv.z) - __logf(sv.z);
    c.w = __logf(yv.w) - __logf(sv.w);
    *reinterpret_cast<f4*>(LL  + b * TT + t4) = a;
    *reinterpret_cast<f4*>(LYS + b * TT + t4) = c;
}

// ---------------------------------------------------------------------------
// Kernel 3: out1 in the EXACT out25 recipe (proven 6.2 TB/s): flat i-mapping
// (i IS the output f4 index), 2048 blocks x 256 thr grid-stride (100% occ),
// reads direct from L2 (X 2MB + LYS/LL 4MB d_ws, ~6MB total), no LDS, no
// barriers, nt stores. Value branch diverges; store is full-wave.
// PRE=0 fallback: inline logs (only for col<7 lanes).
// ---------------------------------------------------------------------------
template<int PRE>
__global__ __launch_bounds__(256) void k_out1_flat(const float* __restrict__ P1,
        const float* __restrict__ P2, const float* __restrict__ Yg,
        const float* __restrict__ X, const float* __restrict__ S,
        f4* __restrict__ out1) {
    int i = blockIdx.x * blockDim.x + threadIdx.x;
    const int stride = gridDim.x * blockDim.x;
    for (; i < NF1; i += stride) {
        int wb  = i / 36;
        int col = i - wb * 36;
        int b   = wb & (BB - 1);
        int w   = wb >> 10;
        f4 v;
        if (col < 7) {
            if (PRE) {
                v = ld4u(P2 + b * TT + w + (col << 2));     // LYS
                float l = P1[b * TT + w + 27];               // LL
                v.x -= l; v.y -= l; v.z -= l; v.w -= l;
            } else {
                int t = w + (col << 2);
                f4 yv = ld4u(Yg + b * TT + t);
                f4 sv = ld4u(P2 + b * SLEN + t);
                float le = P1[b * TT + w + 27];
                v.x = __logf(__fdividef(yv.x, le * sv.x));
                v.y = __logf(__fdividef(yv.y, le * sv.y));
                v.z = __logf(__fdividef(yv.z, le * sv.z));
                v.w = __logf(__fdividef(yv.w, le * sv.w));
            }
        } else if (col < 35) {
            int ch = (col >= 21) ? 1 : 0;
            v = ld4u(X + (size_t)(b * 2 + ch) * TT + w + ((col - 7 - 14 * ch) << 2));
        } else {
            v = *reinterpret_cast<const f4*>(S + (b << 2));
        }
        __builtin_nontemporal_store(v, &out1[i]);
    }
}

// ---------------------------------------------------------------------------
// Kernel 4: out2 + out5 (proven ~6.2 TB/s, unchanged).
// ---------------------------------------------------------------------------
__global__ __launch_bounds__(256) void k_out25(const float* __restrict__ Y,
        const float* __restrict__ mask, f4* __restrict__ out2,
        f4* __restrict__ out5) {
    int i = blockIdx.x * blockDim.x + threadIdx.x;
    const int stride = gridDim.x * blockDim.x;
    for (; i < NF2; i += stride) {
        int wb = i / 7;
        int j  = i - wb * 7;
        int b  = wb & (BB - 1);
        int w  = wb >> 10;
        int base = w + NIN + (j << 2);
        f4 vy = ld4u(Y    + b * TT + base);
        f4 vm = ld4u(mask + b * TT + base);
        __builtin_nontemporal_store(vy, &out2[i]);
        __builtin_nontemporal_store(vm, &out5[i]);
    }
}

extern "C" void kernel_launch(void* const* d_in, const int* in_sizes, int n_in,
                              void* d_out, int out_size, void* d_ws, size_t ws_size,
                              hipStream_t stream) {
    const float* S    = (const float*)d_in[0];
    const float* Y    = (const float*)d_in[1];
    const float* X    = (const float*)d_in[2];
    const int*   idxs = (const int*)d_in[3];
    const float* mask = (const float*)d_in[4];
    const float* EW   = (const float*)d_in[5];

    float* out  = (float*)d_out;
    float* out1 = out;
    float* out2 = out1 + OUT1_SZ;
    float* out3 = out2 + OUT2_SZ;        // levels
    float* out4 = out3 + OUT3_SZ;        // seasonalities
    float* out5 = out4 + OUT4_SZ;        // mask_w

    es_scan<<<16, 64, 0, stream>>>(Y, idxs, EW, out3, out4);

    const size_t need = (size_t)2 * BB * TT * sizeof(float);   // 4 MB
    if (ws_size >= need) {
        float* LL  = (float*)d_ws;
        float* LYS = LL + BB * TT;
        k_pre<<<512, 256, 0, stream>>>(out3, out4, Y, LL, LYS);
        k_out1_flat<1><<<2048, 256, 0, stream>>>(LL, LYS, Y, X, S, (f4*)out1);
    } else {
        k_out1_flat<0><<<2048, 256, 0, stream>>>(out3, out4, Y, X, S, (f4*)out1);
    }
    k_out25<<<2048, 256, 0, stream>>>(Y, mask, (f4*)out2, (f4*)out5);
}